// Round 14
// baseline (2630.986 us; speedup 1.0000x reference)
//
#include <hip/hip_runtime.h>
#include <math.h>

#define D 128
#define NBUCK_MAX 1024     // runtime nbuck = ceil(N/128) = 782
#define NB_EDGE   256      // edge-chunk blocks for the placement pass
#define CAPSEG    40       // slots per (bucket,chunk) segment; lambda=8 -> P(overflow)~1e-15
#define CAPB      4096     // dense col_idx slots per bucket (lambda=2048)
#define CAPE      2600     // LDS edge buffer per bucket (lambda=2048, +12 sigma)

typedef unsigned short u16;
typedef unsigned int   u32;
typedef __attribute__((ext_vector_type(8))) short short8;   // 8 bf16 = 4 VGPRs (MFMA A/B frag)
typedef __attribute__((ext_vector_type(4))) float f32x4;    // MFMA C/D frag
typedef __attribute__((ext_vector_type(2))) float f32x2;

static __device__ __forceinline__ u16 f32_to_bf16(float f) {
    u32 u = __builtin_bit_cast(u32, f);
    u32 r = (u + 0x7FFFu + ((u >> 16) & 1u)) >> 16;          // RNE
    return (u16)r;
}
static __device__ __forceinline__ u32 pack_bf16x2(float lo, float hi) {
    return (u32)f32_to_bf16(lo) | ((u32)f32_to_bf16(hi) << 16);
}
static __device__ __forceinline__ float bf16lo_to_f32(u32 v) {
    return __builtin_bit_cast(float, v << 16);
}
static __device__ __forceinline__ float bf16hi_to_f32(u32 v) {
    return __builtin_bit_cast(float, v & 0xFFFF0000u);
}

// ---------------- dispatch 1: single-pass placement (static segments) + goff scan + W/Wf pack ----------------
// edgeBuf segment for (bucket bk, chunk c): [(bk*NB_EDGE + c)*CAPSEG, +CAPSEG); count segCount[c*nbuck + bk].
__global__ __launch_bounds__(512) void prep_place(const int* __restrict__ src, const int* __restrict__ dst,
                                                  int E, int nbuck,
                                                  u32* __restrict__ edgeBuf, int* __restrict__ segCount,
                                                  const float* __restrict__ W0, const float* __restrict__ W1,
                                                  u16* __restrict__ Wp0, u16* __restrict__ Wp1,
                                                  const float* __restrict__ Wf, float* __restrict__ Wfp,
                                                  const int* __restrict__ gsz, int G, int* __restrict__ goff) {
    const int b = blockIdx.x;
    const int tid = threadIdx.x;
    if (b < NB_EDGE) {
        __shared__ int cur[NBUCK_MAX];
        for (int i = tid; i < nbuck; i += 512) cur[i] = 0;
        __syncthreads();
        int per = (E + NB_EDGE - 1) / NB_EDGE;
        int s = b * per, e = min(E, s + per);
        for (int i = s + tid; i < e; i += 512) {
            int d = dst[i];
            int bk = d >> 7;
            int pos = atomicAdd(&cur[bk], 1);
            if (pos < CAPSEG)
                edgeBuf[((size_t)bk * NB_EDGE + b) * CAPSEG + pos] = (u32)src[i] | ((u32)(d & 127) << 20);
        }
        __syncthreads();
        for (int i = tid; i < nbuck; i += 512) segCount[b * nbuck + i] = min(cur[i], CAPSEG);
    } else if (b == NB_EDGE) {
        // exclusive scan of graph sizes -> goff[0..G] (sentinel)
        __shared__ int wsum[8];
        int base = tid * 4;
        int v[4];
        #pragma unroll
        for (int k = 0; k < 4; k++) v[k] = (base + k < G) ? gsz[base + k] : 0;
        int s = v[0] + v[1] + v[2] + v[3];
        int lane = tid & 63;
        int incl = s;
        #pragma unroll
        for (int off = 1; off < 64; off <<= 1) { int t = __shfl_up(incl, off); if (lane >= off) incl += t; }
        int wv = tid >> 6;
        if (lane == 63) wsum[wv] = incl;
        __syncthreads();
        int woff = 0;
        for (int w = 0; w < wv; w++) woff += wsum[w];
        int run = woff + incl - s;
        #pragma unroll
        for (int k = 0; k < 4; k++) {
            if (base + k <= G) goff[base + k] = run;
            run += v[k];
        }
    } else if (b == NB_EDGE + 1) {
        // Wf pack: Wfp[lane*24 + k*3 + j] = Wf[((lane&15)*8+k)*12 + 3*(lane>>4)+j]
        for (int i = tid; i < 64 * 24; i += 512) {
            int lane = i / 24, r = i % 24, k = r / 3, j = r % 3;
            Wfp[i] = Wf[(((lane & 15) * 8) + k) * 12 + 3 * (lane >> 4) + j];
        }
    } else {
        // W pack: Wp[((nt*4+kt)*64 + lane)*8 + j] = bf16( W[kt*32+(lane>>4)*8+j][nt*16+(lane&15)] )
        int gidx = (b - (NB_EDGE + 2)) * 512 + tid;          // 0 .. 32767
        const float* W = (gidx < 128 * 128) ? W0 : W1;
        u16* Wp = (gidx < 128 * 128) ? Wp0 : Wp1;
        int idx = gidx & (128 * 128 - 1);
        int j = idx & 7, lane = (idx >> 3) & 63, kt = (idx >> 9) & 3, nt = idx >> 11;
        int k = kt * 32 + ((lane >> 4) << 3) + j;
        int n = nt * 16 + (lane & 15);
        Wp[idx] = f32_to_bf16(W[k * 128 + n]);
    }
}

// ---------------- MFMA GEMM core (64-row tiles; used by finalize_gemm0) ----------------
static __device__ __forceinline__ void gemm_body(const short8 af[4], const u16* __restrict__ Wp,
                                                 u16* __restrict__ outb, int N, int row0,
                                                 int tid, int wave, int lane, int quad, int l16,
                                                 u16* Cs) {
    f32x4 acc[8];
    #pragma unroll
    for (int nt = 0; nt < 8; nt++) acc[nt] = (f32x4){0.f, 0.f, 0.f, 0.f};
    #pragma unroll
    for (int kt = 0; kt < 4; kt++) {
        #pragma unroll
        for (int nt = 0; nt < 8; nt++) {
            short8 bf = *(const short8*)(Wp + ((size_t)(nt * 4 + kt) * 64 + lane) * 8);
            acc[nt] = __builtin_amdgcn_mfma_f32_16x16x32_bf16(af[kt], bf, acc[nt], 0, 0, 0);
        }
    }
    // C layout col=lane&15, row=quad*4+reg -> LDS transpose -> coalesced bf16 store
    #pragma unroll
    for (int nt = 0; nt < 8; nt++) {
        #pragma unroll
        for (int r = 0; r < 4; r++) {
            int rl = wave * 16 + quad * 4 + r;
            Cs[rl * 136 + nt * 16 + l16] = f32_to_bf16(acc[nt][r]);
        }
    }
    __syncthreads();
    for (int i = tid; i < 64 * 16; i += 256) {
        int row = i >> 4, chunk = i & 15;
        int grow = row0 + row;
        if (grow <= N)      // row N = zero pad row for agg tail lanes
            *(uint4*)(outb + (size_t)grow * 128 + chunk * 8) =
                *(const uint4*)(Cs + row * 136 + chunk * 8);
    }
}

// ---------------- dispatch 2: csr finalize (binary-search compact) + layer-0 gemm + graph maps ----------------
__global__ __launch_bounds__(256) void finalize_gemm0(const u32* __restrict__ edgeBuf,
                                                      const int* __restrict__ segCount,
                                                      int2* __restrict__ rowse, int* __restrict__ col_idx,
                                                      int nbuck, int gemmGrid,
                                                      const float* __restrict__ A, const u16* __restrict__ Wp,
                                                      u16* __restrict__ outb, int N,
                                                      const int* __restrict__ goff, int G,
                                                      int* __restrict__ node2graph, int* __restrict__ gdone) {
    __shared__ u16 Cs[64 * 136];     // 17408 B, reused as int scratch by the finalize branch
    const int tid = threadIdx.x;
    if ((int)blockIdx.x < nbuck) {
        int* iCs   = (int*)Cs;
        u32* eL    = (u32*)iCs;          // [0, CAPE)  compacted edges
        int* hist  = iCs + CAPE;         // 128
        int* lcur  = iCs + CAPE + 128;   // 128
        int* scnt  = iCs + CAPE + 256;   // 256 seg counts
        int* sbase = iCs + CAPE + 512;   // 257 seg bases (sentinel)  -> total 13480 B < 17408
        const int b = blockIdx.x;
        const size_t ebase = (size_t)b * NB_EDGE * CAPSEG;
        for (int i = tid; i < NB_EDGE; i += 256) scnt[i] = segCount[i * nbuck + b];
        if (tid < 128) hist[tid] = 0;
        __syncthreads();
        if (tid < 64) {              // wave 0: exclusive scan of 256 seg counts + total sentinel
            int carry = 0;
            #pragma unroll
            for (int c4 = 0; c4 < NB_EDGE / 64; c4++) {
                int v = scnt[c4 * 64 + tid];
                int incl = v;
                #pragma unroll
                for (int off = 1; off < 64; off <<= 1) { int t = __shfl_up(incl, off); if (tid >= off) incl += t; }
                sbase[c4 * 64 + tid] = carry + incl - v;
                carry += __shfl(incl, 63);
            }
            if (tid == 0) sbase[NB_EDGE] = carry;
        }
        __syncthreads();
        const int nE = min(sbase[NB_EDGE], CAPE);
        // compact: output position p -> segment via 8-step binary search; dense coalesced reads
        for (int p = tid; p < nE; p += 256) {
            int lo = 0, hi = NB_EDGE;
            #pragma unroll
            for (int s = 0; s < 8; s++) {
                int mid = (lo + hi) >> 1;
                if (sbase[mid] <= p) lo = mid; else hi = mid;
            }
            eL[p] = edgeBuf[ebase + (size_t)lo * CAPSEG + (p - sbase[lo])];
        }
        __syncthreads();
        for (int i = tid; i < nE; i += 256)
            atomicAdd(&hist[(int)(eL[i] >> 20)], 1);
        __syncthreads();
        if (tid < 64) {
            int v0 = hist[tid * 2], v1 = hist[tid * 2 + 1];
            int s = v0 + v1;
            int incl = s;
            #pragma unroll
            for (int off = 1; off < 64; off <<= 1) { int t = __shfl_up(incl, off); if (tid >= off) incl += t; }
            int excl = incl - s;
            lcur[tid * 2] = excl;
            lcur[tid * 2 + 1] = excl + v0;
            int node = b * 128 + tid * 2;
            int st = b * CAPB + excl;
            if (node < N) rowse[node] = make_int2(st, st + v0);
            if (node + 1 < N) rowse[node + 1] = make_int2(st + v0, st + v0 + v1);
        }
        __syncthreads();
        for (int i = tid; i < nE; i += 256) {
            u32 p = eL[i];
            int pos = atomicAdd(&lcur[p >> 20], 1);
            col_idx[b * CAPB + pos] = (int)(p & 0xFFFFFu);
        }
    } else if ((int)blockIdx.x < nbuck + gemmGrid) {
        const int bid = blockIdx.x - nbuck;
        const int wave = tid >> 6, lane = tid & 63, quad = lane >> 4, l16 = lane & 15;
        const int row0 = bid * 64;
        const int arow = row0 + wave * 16 + l16;
        union { u32 u[4]; short8 s; } cv;
        short8 af[4];
        if (arow < N) {
            const float* ab = A + (size_t)arow * 128 + quad * 8;
            #pragma unroll
            for (int kt = 0; kt < 4; kt++) {
                float4 x0 = *(const float4*)(ab + kt * 32);
                float4 x1 = *(const float4*)(ab + kt * 32 + 4);
                cv.u[0] = pack_bf16x2(x0.x, x0.y);
                cv.u[1] = pack_bf16x2(x0.z, x0.w);
                cv.u[2] = pack_bf16x2(x1.x, x1.y);
                cv.u[3] = pack_bf16x2(x1.z, x1.w);
                af[kt] = cv.s;
            }
        } else {
            short8 z = {0, 0, 0, 0, 0, 0, 0, 0};
            #pragma unroll
            for (int kt = 0; kt < 4; kt++) af[kt] = z;
        }
        gemm_body(af, Wp, outb, N, row0, tid, wave, lane, quad, l16, Cs);
    } else {
        // graph maps: node2graph fill + gdone zero (goff is from dispatch 1 — safe)
        int g = blockIdx.x - nbuck - gemmGrid;
        if (g >= G) return;
        int start = goff[g], end = goff[g + 1];
        for (int i = start + tid; i < end; i += 256) node2graph[i] = g;
        if (tid == 0) gdone[(size_t)g * 16] = 0;
    }
}

// ---------------- shared gather core: returns relu(sum + self + bias) slice in r[8] ----------------
static __device__ __forceinline__ void add_row(f32x2* acc, uint4 u) {
    acc[0] += (f32x2){bf16lo_to_f32(u.x), bf16hi_to_f32(u.x)};
    acc[1] += (f32x2){bf16lo_to_f32(u.y), bf16hi_to_f32(u.y)};
    acc[2] += (f32x2){bf16lo_to_f32(u.z), bf16hi_to_f32(u.z)};
    acc[3] += (f32x2){bf16lo_to_f32(u.w), bf16hi_to_f32(u.w)};
}

static __device__ __forceinline__ void gather_core(const u16* __restrict__ xwb, const int2* __restrict__ rowse,
                                                   const int* __restrict__ col_idx, const float* __restrict__ bias,
                                                   int wid, int lane, int N, int q, int d8, float r[8]) {
    f32x2 acc[4];
    #pragma unroll
    for (int t = 0; t < 4; t++) acc[t] = (f32x2){0.f, 0.f};
    int2 se = rowse[wid];
    int start = se.x, end = se.y;
    for (int e = start; e < end; e += 64) {
        int idx = e + lane;
        int j = (idx < end) ? col_idx[idx] : N;   // tail -> shared zero row
        int cnt = min(64, end - e);
        for (int i = 0; i < cnt; i += 16) {
            int j0 = __shfl(j, i + q);
            int j1 = __shfl(j, i + 4 + q);
            int j2 = __shfl(j, i + 8 + q);
            int j3 = __shfl(j, i + 12 + q);
            uint4 r0 = *(const uint4*)(xwb + (size_t)j0 * D + d8);
            uint4 r1 = *(const uint4*)(xwb + (size_t)j1 * D + d8);
            uint4 r2 = *(const uint4*)(xwb + (size_t)j2 * D + d8);
            uint4 r3 = *(const uint4*)(xwb + (size_t)j3 * D + d8);
            add_row(acc, r0);
            add_row(acc, r1);
            add_row(acc, r2);
            add_row(acc, r3);
        }
    }
    float av[8] = {acc[0].x, acc[0].y, acc[1].x, acc[1].y, acc[2].x, acc[2].y, acc[3].x, acc[3].y};
    #pragma unroll
    for (int t = 0; t < 8; t++) {
        av[t] += __shfl_xor(av[t], 16);
        av[t] += __shfl_xor(av[t], 32);
    }
    uint4 sv = *(const uint4*)(xwb + (size_t)wid * D + d8);
    float4 ba = *(const float4*)(bias + d8);
    float4 bb = *(const float4*)(bias + d8 + 4);
    r[0] = fmaxf(av[0] + bf16lo_to_f32(sv.x) + ba.x, 0.f);
    r[1] = fmaxf(av[1] + bf16hi_to_f32(sv.x) + ba.y, 0.f);
    r[2] = fmaxf(av[2] + bf16lo_to_f32(sv.y) + ba.z, 0.f);
    r[3] = fmaxf(av[3] + bf16hi_to_f32(sv.y) + ba.w, 0.f);
    r[4] = fmaxf(av[4] + bf16lo_to_f32(sv.z) + bb.x, 0.f);
    r[5] = fmaxf(av[5] + bf16hi_to_f32(sv.z) + bb.y, 0.f);
    r[6] = fmaxf(av[6] + bf16lo_to_f32(sv.w) + bb.z, 0.f);
    r[7] = fmaxf(av[7] + bf16hi_to_f32(sv.w) + bb.w, 0.f);
}

// ---------------- dispatch 3: fused layer-1 aggregate + layer-1 GEMM ----------------
// block = 16 nodes, 4 waves. Wave w gathers nodes w*4..w*4+3 -> bf16 h rows in LDS (pad 136);
// then wave w computes output cols 32w..32w+31 via 8 MFMAs; LDS transpose; coalesced store.
__global__ __launch_bounds__(256) void agg_gemm1(const u16* __restrict__ xwb, const int2* __restrict__ rowse,
                                                 const int* __restrict__ col_idx, const float* __restrict__ bias,
                                                 const u16* __restrict__ Wp, u16* __restrict__ outb, int N) {
    __shared__ u16 hs[16 * 136];
    __shared__ u16 Cs[16 * 136];
    const int tid = threadIdx.x;
    const int wave = tid >> 6, lane = tid & 63, quad = lane >> 4, l16 = lane & 15;
    const int tile = blockIdx.x * 16;
    const int d8 = l16 * 8;
    #pragma unroll
    for (int m = 0; m < 4; m++) {
        int nodeLocal = wave * 4 + m;
        int wid = tile + nodeLocal;
        if (wid < N) {
            float r[8];
            gather_core(xwb, rowse, col_idx, bias, wid, lane, N, quad, d8, r);
            if (quad == 0) {
                uint4 o;
                o.x = pack_bf16x2(r[0], r[1]);
                o.y = pack_bf16x2(r[2], r[3]);
                o.z = pack_bf16x2(r[4], r[5]);
                o.w = pack_bf16x2(r[6], r[7]);
                *(uint4*)(hs + nodeLocal * 136 + d8) = o;
            }
        } else if (quad == 0) {
            *(uint4*)(hs + nodeLocal * 136 + d8) = make_uint4(0, 0, 0, 0);
        }
    }
    __syncthreads();
    // A-frags from LDS: row m = l16, k = kt*32 + quad*8 + j  (stride 136 -> <=2-way bank alias)
    short8 af[4];
    #pragma unroll
    for (int kt = 0; kt < 4; kt++)
        af[kt] = *(const short8*)(hs + l16 * 136 + kt * 32 + quad * 8);
    f32x4 acc[2];
    acc[0] = (f32x4){0.f, 0.f, 0.f, 0.f};
    acc[1] = (f32x4){0.f, 0.f, 0.f, 0.f};
    #pragma unroll
    for (int kt = 0; kt < 4; kt++) {
        #pragma unroll
        for (int t = 0; t < 2; t++) {
            int nt = wave * 2 + t;
            short8 bf = *(const short8*)(Wp + ((size_t)(nt * 4 + kt) * 64 + lane) * 8);
            acc[t] = __builtin_amdgcn_mfma_f32_16x16x32_bf16(af[kt], bf, acc[t], 0, 0, 0);
        }
    }
    // C layout col=lane&15 (within nt tile), row=quad*4+reg -> Cs transpose
    #pragma unroll
    for (int t = 0; t < 2; t++) {
        int nt = wave * 2 + t;
        #pragma unroll
        for (int r = 0; r < 4; r++)
            Cs[(quad * 4 + r) * 136 + nt * 16 + l16] = f32_to_bf16(acc[t][r]);
    }
    __syncthreads();
    // coalesced store: 16 rows x 16 uint4 chunks = 256 threads, one each
    {
        int row = tid >> 4, chunk = tid & 15;
        int grow = tile + row;
        if (grow <= N)      // row N = zero pad row for agg_head tails
            *(uint4*)(outb + (size_t)grow * 128 + chunk * 8) =
                *(const uint4*)(Cs + row * 136 + chunk * 8);
    }
}

// ---------------- dispatch 4: layer-2 aggregate + head + fused per-graph mean (done-counter) ----------------
__global__ __launch_bounds__(256) void agg_head(const u16* __restrict__ xwb, const int2* __restrict__ rowse,
                                                const int* __restrict__ col_idx, const float* __restrict__ bias,
                                                const float* __restrict__ Wfp, const float* __restrict__ bfv,
                                                const int* __restrict__ node2graph, const int* __restrict__ goff,
                                                int* __restrict__ gdone, float* __restrict__ out12,
                                                float* __restrict__ out, int N) {
    int wid = (blockIdx.x * 256 + threadIdx.x) >> 6;
    int lane = threadIdx.x & 63;
    if (wid >= N) return;
    const int q = lane >> 4;
    const int d8 = (lane & 15) * 8;
    // issue head-weight loads early (independent of gather) — 6 coalesced float4
    float w[24];
    const float* wp = Wfp + lane * 24;
    #pragma unroll
    for (int i = 0; i < 6; i++) *(float4*)(w + i * 4) = *(const float4*)(wp + i * 4);
    float r[8];
    gather_core(xwb, rowse, col_idx, bias, wid, lane, N, q, d8, r);
    const int t0 = 3 * q;
    float p0 = 0.f, p1 = 0.f, p2 = 0.f;
    #pragma unroll
    for (int k = 0; k < 8; k++) {
        p0 += r[k] * w[k * 3];
        p1 += r[k] * w[k * 3 + 1];
        p2 += r[k] * w[k * 3 + 2];
    }
    #pragma unroll
    for (int m = 1; m <= 8; m <<= 1) {
        p0 += __shfl_xor(p0, m);
        p1 += __shfl_xor(p1, m);
        p2 += __shfl_xor(p2, m);
    }
    if ((lane & 15) == 0) {
        float s0 = 1.f / (1.f + __expf(-(p0 + bfv[t0])));
        float s1 = 1.f / (1.f + __expf(-(p1 + bfv[t0 + 1])));
        float s2 = 1.f / (1.f + __expf(-(p2 + bfv[t0 + 2])));
        float* o = out12 + (size_t)wid * 12 + t0;
        o[0] = s0; o[1] = s1; o[2] = s2;
    }
    // ---- fused per-graph mean: last wave of each graph reduces it ----
    int g = node2graph[wid];
    int startg = goff[g], endg = goff[g + 1];
    int sz = endg - startg;
    __threadfence();                               // release: out12 stores visible before count
    int old = 0;
    if (lane == 0) old = atomicAdd(&gdone[(size_t)g * 16], 1);
    old = __shfl(old, 0);
    if (old == sz - 1) {
        __threadfence();                           // acquire: other waves' out12 now visible
        float s = 0.f;
        if (lane < 48) {
            int t = lane % 12, c = lane / 12;      // 4 chunks x 12 tasks
            for (int n = c; n < sz; n += 4)
                s += out12[(size_t)(startg + n) * 12 + t];
        }
        s += __shfl_down(s, 24);
        s += __shfl_down(s, 12);
        if (lane < 12) out[(size_t)g * 12 + lane] = s / (float)sz;
    }
}

// ---------------- launch ----------------

extern "C" void kernel_launch(void* const* d_in, const int* in_sizes, int n_in,
                              void* d_out, int out_size, void* d_ws, size_t ws_size,
                              hipStream_t stream) {
    const float* X   = (const float*)d_in[0];
    const int* edges = (const int*)d_in[1];
    const int* gsz   = (const int*)d_in[2];
    const float* W0  = (const float*)d_in[3];
    const float* b0  = (const float*)d_in[4];
    const float* W1  = (const float*)d_in[5];
    const float* b1  = (const float*)d_in[6];
    const float* Wf  = (const float*)d_in[7];
    const float* bfv = (const float*)d_in[8];
    float* out = (float*)d_out;

    const int N = in_sizes[0] / D;       // 100000
    const int E = in_sizes[1] / 2;       // 1600000
    const int G = in_sizes[2];           // 1000
    const int* esrc = edges;
    const int* edst = edges + E;
    const int nbuck = (N + 127) >> 7;    // 782

    // workspace layout (xwb/hb get N+64 rows: row N is the zero pad row)
    char* ws = (char*)d_ws;
    char* p = ws;
    u16* xwb     = (u16*)p;  p += (((size_t)(N + 64) * D * 2) + 255) & ~255ull;
    u16* hb      = (u16*)p;  p += (((size_t)(N + 64) * D * 2) + 255) & ~255ull;
    u16* Wp0     = (u16*)p;  p += ((size_t)128 * 128 * 2 + 255) & ~255ull;
    u16* Wp1     = (u16*)p;  p += ((size_t)128 * 128 * 2 + 255) & ~255ull;
    float* Wfp   = (float*)p; p += ((size_t)64 * 24 * 4 + 255) & ~255ull;
    u32* edgeBuf = (u32*)p;  p += (((size_t)nbuck * NB_EDGE * CAPSEG * 4) + 255) & ~255ull;  // 32 MB
    int* segCount = (int*)p; p += (((size_t)NB_EDGE * NBUCK_MAX * 4) + 255) & ~255ull;       // 1 MB
    int* col_idx = (int*)p;  p += (((size_t)nbuck * CAPB * 4) + 255) & ~255ull;              // 12.8 MB
    int2* rowse  = (int2*)p; p += (((size_t)N * 8) + 255) & ~255ull;
    float* out12 = (float*)p; p += (((size_t)N * 12 * 4) + 255) & ~255ull;                   // 4.8 MB
    int* node2graph = (int*)p; p += (((size_t)N * 4) + 255) & ~255ull;
    int* gdone   = (int*)p;  p += (((size_t)NBUCK_MAX * 16 * 4) + 255) & ~255ull;            // padded: 1 line/graph
    int* goff    = (int*)p;

    // 1: single-pass placement + goff scan + Wf pack + W pack
    prep_place<<<NB_EDGE + 2 + 64, 512, 0, stream>>>(esrc, edst, E, nbuck, edgeBuf, segCount,
                                                     W0, W1, Wp0, Wp1, Wf, Wfp, gsz, G, goff);
    // 2: CSR finalize (binary-search compact) + layer-0 GEMM + graph maps
    const int gemmGrid = (N + 63) / 64;
    finalize_gemm0<<<nbuck + gemmGrid + G, 256, 0, stream>>>(edgeBuf, segCount, rowse, col_idx,
                                                             nbuck, gemmGrid, X, Wp0, xwb, N,
                                                             goff, G, node2graph, gdone);
    // 3: fused layer-1 aggregate + layer-1 GEMM (writes xw2 into hb, incl. zero row N)
    agg_gemm1<<<N / 16 + 1, 256, 0, stream>>>(xwb, rowse, col_idx, b0, Wp1, hb, N);
    // 4: layer-2 aggregate + head + fused per-graph mean
    agg_head<<<(N * 64 + 255) / 256, 256, 0, stream>>>(hb, rowse, col_idx, b1, Wfp, bfv,
                                                       node2graph, goff, gdone, out12, out, N);
}

// Round 15
// 277.098 us; speedup vs baseline: 9.4948x; 9.4948x over previous
//
#include <hip/hip_runtime.h>
#include <math.h>

#define D 128
#define NBUCK_MAX 1024     // runtime nbuck = ceil(N/128) = 782
#define NB_EDGE   256      // edge-chunk blocks for the placement pass
#define CAPSEG    40       // slots per (bucket,chunk) segment; lambda=8 -> P(overflow)~1e-15
#define CAPB      4096     // dense col_idx slots per bucket (lambda=2048)
#define CAPE      2600     // LDS edge buffer per bucket (lambda=2048, +12 sigma)

typedef unsigned short u16;
typedef unsigned int   u32;
typedef __attribute__((ext_vector_type(8))) short short8;   // 8 bf16 = 4 VGPRs (MFMA A/B frag)
typedef __attribute__((ext_vector_type(4))) float f32x4;    // MFMA C/D frag
typedef __attribute__((ext_vector_type(2))) float f32x2;

static __device__ __forceinline__ u16 f32_to_bf16(float f) {
    u32 u = __builtin_bit_cast(u32, f);
    u32 r = (u + 0x7FFFu + ((u >> 16) & 1u)) >> 16;          // RNE
    return (u16)r;
}
static __device__ __forceinline__ u32 pack_bf16x2(float lo, float hi) {
    return (u32)f32_to_bf16(lo) | ((u32)f32_to_bf16(hi) << 16);
}
static __device__ __forceinline__ float bf16lo_to_f32(u32 v) {
    return __builtin_bit_cast(float, v << 16);
}
static __device__ __forceinline__ float bf16hi_to_f32(u32 v) {
    return __builtin_bit_cast(float, v & 0xFFFF0000u);
}

// ---------------- dispatch 1: single-pass placement (static segments) + goff scan + W/Wf pack ----------------
// edgeBuf segment for (bucket bk, chunk c): [(bk*NB_EDGE + c)*CAPSEG, +CAPSEG); count segCount[c*nbuck + bk].
__global__ __launch_bounds__(512) void prep_place(const int* __restrict__ src, const int* __restrict__ dst,
                                                  int E, int nbuck,
                                                  u32* __restrict__ edgeBuf, int* __restrict__ segCount,
                                                  const float* __restrict__ W0, const float* __restrict__ W1,
                                                  u16* __restrict__ Wp0, u16* __restrict__ Wp1,
                                                  const float* __restrict__ Wf, float* __restrict__ Wfp,
                                                  const int* __restrict__ gsz, int G, int* __restrict__ goff) {
    const int b = blockIdx.x;
    const int tid = threadIdx.x;
    if (b < NB_EDGE) {
        __shared__ int cur[NBUCK_MAX];
        for (int i = tid; i < nbuck; i += 512) cur[i] = 0;
        __syncthreads();
        int per = (E + NB_EDGE - 1) / NB_EDGE;
        int s = b * per, e = min(E, s + per);
        for (int i = s + tid; i < e; i += 512) {
            int d = dst[i];
            int bk = d >> 7;
            int pos = atomicAdd(&cur[bk], 1);
            if (pos < CAPSEG)
                edgeBuf[((size_t)bk * NB_EDGE + b) * CAPSEG + pos] = (u32)src[i] | ((u32)(d & 127) << 20);
        }
        __syncthreads();
        for (int i = tid; i < nbuck; i += 512) segCount[b * nbuck + i] = min(cur[i], CAPSEG);
    } else if (b == NB_EDGE) {
        // exclusive scan of graph sizes -> goff[0..G] (sentinel)
        __shared__ int wsum[8];
        int base = tid * 4;
        int v[4];
        #pragma unroll
        for (int k = 0; k < 4; k++) v[k] = (base + k < G) ? gsz[base + k] : 0;
        int s = v[0] + v[1] + v[2] + v[3];
        int lane = tid & 63;
        int incl = s;
        #pragma unroll
        for (int off = 1; off < 64; off <<= 1) { int t = __shfl_up(incl, off); if (lane >= off) incl += t; }
        int wv = tid >> 6;
        if (lane == 63) wsum[wv] = incl;
        __syncthreads();
        int woff = 0;
        for (int w = 0; w < wv; w++) woff += wsum[w];
        int run = woff + incl - s;
        #pragma unroll
        for (int k = 0; k < 4; k++) {
            if (base + k <= G) goff[base + k] = run;
            run += v[k];
        }
    } else if (b == NB_EDGE + 1) {
        // Wf pack: Wfp[lane*24 + k*3 + j] = Wf[((lane&15)*8+k)*12 + 3*(lane>>4)+j]
        for (int i = tid; i < 64 * 24; i += 512) {
            int lane = i / 24, r = i % 24, k = r / 3, j = r % 3;
            Wfp[i] = Wf[(((lane & 15) * 8) + k) * 12 + 3 * (lane >> 4) + j];
        }
    } else {
        // W pack: Wp[((nt*4+kt)*64 + lane)*8 + j] = bf16( W[kt*32+(lane>>4)*8+j][nt*16+(lane&15)] )
        int gidx = (b - (NB_EDGE + 2)) * 512 + tid;          // 0 .. 32767
        const float* W = (gidx < 128 * 128) ? W0 : W1;
        u16* Wp = (gidx < 128 * 128) ? Wp0 : Wp1;
        int idx = gidx & (128 * 128 - 1);
        int j = idx & 7, lane = (idx >> 3) & 63, kt = (idx >> 9) & 3, nt = idx >> 11;
        int k = kt * 32 + ((lane >> 4) << 3) + j;
        int n = nt * 16 + (lane & 15);
        Wp[idx] = f32_to_bf16(W[k * 128 + n]);
    }
}

// ---------------- MFMA GEMM core (64-row tiles; used by finalize_gemm0) ----------------
static __device__ __forceinline__ void gemm_body(const short8 af[4], const u16* __restrict__ Wp,
                                                 u16* __restrict__ outb, int N, int row0,
                                                 int tid, int wave, int lane, int quad, int l16,
                                                 u16* Cs) {
    f32x4 acc[8];
    #pragma unroll
    for (int nt = 0; nt < 8; nt++) acc[nt] = (f32x4){0.f, 0.f, 0.f, 0.f};
    #pragma unroll
    for (int kt = 0; kt < 4; kt++) {
        #pragma unroll
        for (int nt = 0; nt < 8; nt++) {
            short8 bf = *(const short8*)(Wp + ((size_t)(nt * 4 + kt) * 64 + lane) * 8);
            acc[nt] = __builtin_amdgcn_mfma_f32_16x16x32_bf16(af[kt], bf, acc[nt], 0, 0, 0);
        }
    }
    // C layout col=lane&15, row=quad*4+reg -> LDS transpose -> coalesced bf16 store
    #pragma unroll
    for (int nt = 0; nt < 8; nt++) {
        #pragma unroll
        for (int r = 0; r < 4; r++) {
            int rl = wave * 16 + quad * 4 + r;
            Cs[rl * 136 + nt * 16 + l16] = f32_to_bf16(acc[nt][r]);
        }
    }
    __syncthreads();
    for (int i = tid; i < 64 * 16; i += 256) {
        int row = i >> 4, chunk = i & 15;
        int grow = row0 + row;
        if (grow <= N)      // row N = zero pad row for agg tail lanes
            *(uint4*)(outb + (size_t)grow * 128 + chunk * 8) =
                *(const uint4*)(Cs + row * 136 + chunk * 8);
    }
}

// ---------------- dispatch 2: csr finalize (binary-search compact) + layer-0 gemm ----------------
__global__ __launch_bounds__(256) void finalize_gemm0(const u32* __restrict__ edgeBuf,
                                                      const int* __restrict__ segCount,
                                                      int2* __restrict__ rowse, int* __restrict__ col_idx,
                                                      int nbuck,
                                                      const float* __restrict__ A, const u16* __restrict__ Wp,
                                                      u16* __restrict__ outb, int N) {
    __shared__ u16 Cs[64 * 136];     // 17408 B, reused as int scratch by the finalize branch
    const int tid = threadIdx.x;
    if ((int)blockIdx.x < nbuck) {
        int* iCs   = (int*)Cs;
        u32* eL    = (u32*)iCs;          // [0, CAPE)  compacted edges
        int* hist  = iCs + CAPE;         // 128
        int* lcur  = iCs + CAPE + 128;   // 128
        int* scnt  = iCs + CAPE + 256;   // 256 seg counts
        int* sbase = iCs + CAPE + 512;   // 257 seg bases (sentinel)  -> total 13480 B < 17408
        const int b = blockIdx.x;
        const size_t ebase = (size_t)b * NB_EDGE * CAPSEG;
        for (int i = tid; i < NB_EDGE; i += 256) scnt[i] = segCount[i * nbuck + b];
        if (tid < 128) hist[tid] = 0;
        __syncthreads();
        if (tid < 64) {              // wave 0: exclusive scan of 256 seg counts + total sentinel
            int carry = 0;
            #pragma unroll
            for (int c4 = 0; c4 < NB_EDGE / 64; c4++) {
                int v = scnt[c4 * 64 + tid];
                int incl = v;
                #pragma unroll
                for (int off = 1; off < 64; off <<= 1) { int t = __shfl_up(incl, off); if (tid >= off) incl += t; }
                sbase[c4 * 64 + tid] = carry + incl - v;
                carry += __shfl(incl, 63);
            }
            if (tid == 0) sbase[NB_EDGE] = carry;
        }
        __syncthreads();
        const int nE = min(sbase[NB_EDGE], CAPE);
        // compact: output position p -> segment via 8-step binary search; dense coalesced reads
        for (int p = tid; p < nE; p += 256) {
            int lo = 0, hi = NB_EDGE;
            #pragma unroll
            for (int s = 0; s < 8; s++) {
                int mid = (lo + hi) >> 1;
                if (sbase[mid] <= p) lo = mid; else hi = mid;
            }
            eL[p] = edgeBuf[ebase + (size_t)lo * CAPSEG + (p - sbase[lo])];
        }
        __syncthreads();
        for (int i = tid; i < nE; i += 256)
            atomicAdd(&hist[(int)(eL[i] >> 20)], 1);
        __syncthreads();
        if (tid < 64) {
            int v0 = hist[tid * 2], v1 = hist[tid * 2 + 1];
            int s = v0 + v1;
            int incl = s;
            #pragma unroll
            for (int off = 1; off < 64; off <<= 1) { int t = __shfl_up(incl, off); if (tid >= off) incl += t; }
            int excl = incl - s;
            lcur[tid * 2] = excl;
            lcur[tid * 2 + 1] = excl + v0;
            int node = b * 128 + tid * 2;
            int st = b * CAPB + excl;
            if (node < N) rowse[node] = make_int2(st, st + v0);
            if (node + 1 < N) rowse[node + 1] = make_int2(st + v0, st + v0 + v1);
        }
        __syncthreads();
        for (int i = tid; i < nE; i += 256) {
            u32 p = eL[i];
            int pos = atomicAdd(&lcur[p >> 20], 1);
            col_idx[b * CAPB + pos] = (int)(p & 0xFFFFFu);
        }
    } else {
        const int bid = blockIdx.x - nbuck;
        const int wave = tid >> 6, lane = tid & 63, quad = lane >> 4, l16 = lane & 15;
        const int row0 = bid * 64;
        const int arow = row0 + wave * 16 + l16;
        union { u32 u[4]; short8 s; } cv;
        short8 af[4];
        if (arow < N) {
            const float* ab = A + (size_t)arow * 128 + quad * 8;
            #pragma unroll
            for (int kt = 0; kt < 4; kt++) {
                float4 x0 = *(const float4*)(ab + kt * 32);
                float4 x1 = *(const float4*)(ab + kt * 32 + 4);
                cv.u[0] = pack_bf16x2(x0.x, x0.y);
                cv.u[1] = pack_bf16x2(x0.z, x0.w);
                cv.u[2] = pack_bf16x2(x1.x, x1.y);
                cv.u[3] = pack_bf16x2(x1.z, x1.w);
                af[kt] = cv.s;
            }
        } else {
            short8 z = {0, 0, 0, 0, 0, 0, 0, 0};
            #pragma unroll
            for (int kt = 0; kt < 4; kt++) af[kt] = z;
        }
        gemm_body(af, Wp, outb, N, row0, tid, wave, lane, quad, l16, Cs);
    }
}

// ---------------- shared gather core: returns relu(sum + self + bias) slice in r[8] ----------------
static __device__ __forceinline__ void add_row(f32x2* acc, uint4 u) {
    acc[0] += (f32x2){bf16lo_to_f32(u.x), bf16hi_to_f32(u.x)};
    acc[1] += (f32x2){bf16lo_to_f32(u.y), bf16hi_to_f32(u.y)};
    acc[2] += (f32x2){bf16lo_to_f32(u.z), bf16hi_to_f32(u.z)};
    acc[3] += (f32x2){bf16lo_to_f32(u.w), bf16hi_to_f32(u.w)};
}

static __device__ __forceinline__ void gather_core(const u16* __restrict__ xwb, const int2* __restrict__ rowse,
                                                   const int* __restrict__ col_idx, const float* __restrict__ bias,
                                                   int wid, int lane, int N, int q, int d8, float r[8]) {
    f32x2 acc[4];
    #pragma unroll
    for (int t = 0; t < 4; t++) acc[t] = (f32x2){0.f, 0.f};
    int2 se = rowse[wid];
    int start = se.x, end = se.y;
    for (int e = start; e < end; e += 64) {
        int idx = e + lane;
        int j = (idx < end) ? col_idx[idx] : N;   // tail -> shared zero row
        int cnt = min(64, end - e);
        for (int i = 0; i < cnt; i += 16) {
            int j0 = __shfl(j, i + q);
            int j1 = __shfl(j, i + 4 + q);
            int j2 = __shfl(j, i + 8 + q);
            int j3 = __shfl(j, i + 12 + q);
            uint4 r0 = *(const uint4*)(xwb + (size_t)j0 * D + d8);
            uint4 r1 = *(const uint4*)(xwb + (size_t)j1 * D + d8);
            uint4 r2 = *(const uint4*)(xwb + (size_t)j2 * D + d8);
            uint4 r3 = *(const uint4*)(xwb + (size_t)j3 * D + d8);
            add_row(acc, r0);
            add_row(acc, r1);
            add_row(acc, r2);
            add_row(acc, r3);
        }
    }
    float av[8] = {acc[0].x, acc[0].y, acc[1].x, acc[1].y, acc[2].x, acc[2].y, acc[3].x, acc[3].y};
    #pragma unroll
    for (int t = 0; t < 8; t++) {
        av[t] += __shfl_xor(av[t], 16);
        av[t] += __shfl_xor(av[t], 32);
    }
    uint4 sv = *(const uint4*)(xwb + (size_t)wid * D + d8);
    float4 ba = *(const float4*)(bias + d8);
    float4 bb = *(const float4*)(bias + d8 + 4);
    r[0] = fmaxf(av[0] + bf16lo_to_f32(sv.x) + ba.x, 0.f);
    r[1] = fmaxf(av[1] + bf16hi_to_f32(sv.x) + ba.y, 0.f);
    r[2] = fmaxf(av[2] + bf16lo_to_f32(sv.y) + ba.z, 0.f);
    r[3] = fmaxf(av[3] + bf16hi_to_f32(sv.y) + ba.w, 0.f);
    r[4] = fmaxf(av[4] + bf16lo_to_f32(sv.z) + bb.x, 0.f);
    r[5] = fmaxf(av[5] + bf16hi_to_f32(sv.z) + bb.y, 0.f);
    r[6] = fmaxf(av[6] + bf16lo_to_f32(sv.w) + bb.z, 0.f);
    r[7] = fmaxf(av[7] + bf16hi_to_f32(sv.w) + bb.w, 0.f);
}

// ---------------- dispatch 3: fused layer-1 aggregate + layer-1 GEMM ----------------
// block = 16 nodes, 4 waves. Wave w gathers nodes w*4..w*4+3 -> bf16 h rows in LDS (pad 136);
// then wave w computes output cols 32w..32w+31 via 8 MFMAs; LDS transpose; coalesced store.
__global__ __launch_bounds__(256) void agg_gemm1(const u16* __restrict__ xwb, const int2* __restrict__ rowse,
                                                 const int* __restrict__ col_idx, const float* __restrict__ bias,
                                                 const u16* __restrict__ Wp, u16* __restrict__ outb, int N) {
    __shared__ u16 hs[16 * 136];
    __shared__ u16 Cs[16 * 136];
    const int tid = threadIdx.x;
    const int wave = tid >> 6, lane = tid & 63, quad = lane >> 4, l16 = lane & 15;
    const int tile = blockIdx.x * 16;
    const int d8 = l16 * 8;
    #pragma unroll
    for (int m = 0; m < 4; m++) {
        int nodeLocal = wave * 4 + m;
        int wid = tile + nodeLocal;
        if (wid < N) {
            float r[8];
            gather_core(xwb, rowse, col_idx, bias, wid, lane, N, quad, d8, r);
            if (quad == 0) {
                uint4 o;
                o.x = pack_bf16x2(r[0], r[1]);
                o.y = pack_bf16x2(r[2], r[3]);
                o.z = pack_bf16x2(r[4], r[5]);
                o.w = pack_bf16x2(r[6], r[7]);
                *(uint4*)(hs + nodeLocal * 136 + d8) = o;
            }
        } else if (quad == 0) {
            *(uint4*)(hs + nodeLocal * 136 + d8) = make_uint4(0, 0, 0, 0);
        }
    }
    __syncthreads();
    // A-frags from LDS: row m = l16, k = kt*32 + quad*8 + j  (stride 136 -> <=2-way bank alias)
    short8 af[4];
    #pragma unroll
    for (int kt = 0; kt < 4; kt++)
        af[kt] = *(const short8*)(hs + l16 * 136 + kt * 32 + quad * 8);
    f32x4 acc[2];
    acc[0] = (f32x4){0.f, 0.f, 0.f, 0.f};
    acc[1] = (f32x4){0.f, 0.f, 0.f, 0.f};
    #pragma unroll
    for (int kt = 0; kt < 4; kt++) {
        #pragma unroll
        for (int t = 0; t < 2; t++) {
            int nt = wave * 2 + t;
            short8 bf = *(const short8*)(Wp + ((size_t)(nt * 4 + kt) * 64 + lane) * 8);
            acc[t] = __builtin_amdgcn_mfma_f32_16x16x32_bf16(af[kt], bf, acc[t], 0, 0, 0);
        }
    }
    // C layout col=lane&15 (within nt tile), row=quad*4+reg -> Cs transpose
    #pragma unroll
    for (int t = 0; t < 2; t++) {
        int nt = wave * 2 + t;
        #pragma unroll
        for (int r = 0; r < 4; r++)
            Cs[(quad * 4 + r) * 136 + nt * 16 + l16] = f32_to_bf16(acc[t][r]);
    }
    __syncthreads();
    // coalesced store: 16 rows x 16 uint4 chunks = 256 threads, one each
    {
        int row = tid >> 4, chunk = tid & 15;
        int grow = tile + row;
        if (grow <= N)      // row N = zero pad row for agg_head tails
            *(uint4*)(outb + (size_t)grow * 128 + chunk * 8) =
                *(const uint4*)(Cs + row * 136 + chunk * 8);
    }
}

// ---------------- dispatch 4: layer-2 aggregate fused with head -> out12 ----------------
__global__ __launch_bounds__(256) void agg_head(const u16* __restrict__ xwb, const int2* __restrict__ rowse,
                                                const int* __restrict__ col_idx, const float* __restrict__ bias,
                                                const float* __restrict__ Wfp, const float* __restrict__ bfv,
                                                float* __restrict__ out12, int N) {
    int wid = (blockIdx.x * 256 + threadIdx.x) >> 6;
    int lane = threadIdx.x & 63;
    if (wid >= N) return;
    const int q = lane >> 4;
    const int d8 = (lane & 15) * 8;
    // issue head-weight loads early (independent of gather) — 6 coalesced float4
    float w[24];
    const float* wp = Wfp + lane * 24;
    #pragma unroll
    for (int i = 0; i < 6; i++) *(float4*)(w + i * 4) = *(const float4*)(wp + i * 4);
    float r[8];
    gather_core(xwb, rowse, col_idx, bias, wid, lane, N, q, d8, r);
    const int t0 = 3 * q;
    float p0 = 0.f, p1 = 0.f, p2 = 0.f;
    #pragma unroll
    for (int k = 0; k < 8; k++) {
        p0 += r[k] * w[k * 3];
        p1 += r[k] * w[k * 3 + 1];
        p2 += r[k] * w[k * 3 + 2];
    }
    #pragma unroll
    for (int m = 1; m <= 8; m <<= 1) {
        p0 += __shfl_xor(p0, m);
        p1 += __shfl_xor(p1, m);
        p2 += __shfl_xor(p2, m);
    }
    if ((lane & 15) == 0) {
        float s0 = 1.f / (1.f + __expf(-(p0 + bfv[t0])));
        float s1 = 1.f / (1.f + __expf(-(p1 + bfv[t0 + 1])));
        float s2 = 1.f / (1.f + __expf(-(p2 + bfv[t0 + 2])));
        float* o = out12 + (size_t)wid * 12 + t0;
        o[0] = s0; o[1] = s1; o[2] = s2;
    }
}

// ---------------- dispatch 5: per-graph mean over out12 ----------------
__global__ __launch_bounds__(128) void graph_mean(const float* __restrict__ out12, const int* __restrict__ goff,
                                                  float* __restrict__ out, int G) {
    __shared__ float partial[120];
    int g = blockIdx.x;
    int tid = threadIdx.x;
    int start = goff[g];
    int size = goff[g + 1] - start;
    if (tid < 120) {
        int t = tid % 12, chunk = tid / 12;
        float s = 0.f;
        for (int i = chunk; i < size; i += 10)
            s += out12[(size_t)(start + i) * 12 + t];
        partial[tid] = s;
    }
    __syncthreads();
    if (tid < 12) {
        float tot = 0.f;
        #pragma unroll
        for (int c = 0; c < 10; c++) tot += partial[c * 12 + tid];
        out[(size_t)g * 12 + tid] = tot / (float)size;
    }
}

// ---------------- launch ----------------

extern "C" void kernel_launch(void* const* d_in, const int* in_sizes, int n_in,
                              void* d_out, int out_size, void* d_ws, size_t ws_size,
                              hipStream_t stream) {
    const float* X   = (const float*)d_in[0];
    const int* edges = (const int*)d_in[1];
    const int* gsz   = (const int*)d_in[2];
    const float* W0  = (const float*)d_in[3];
    const float* b0  = (const float*)d_in[4];
    const float* W1  = (const float*)d_in[5];
    const float* b1  = (const float*)d_in[6];
    const float* Wf  = (const float*)d_in[7];
    const float* bfv = (const float*)d_in[8];
    float* out = (float*)d_out;

    const int N = in_sizes[0] / D;       // 100000
    const int E = in_sizes[1] / 2;       // 1600000
    const int G = in_sizes[2];           // 1000
    const int* esrc = edges;
    const int* edst = edges + E;
    const int nbuck = (N + 127) >> 7;    // 782

    // workspace layout (xwb/hb get N+64 rows: row N is the zero pad row)
    char* ws = (char*)d_ws;
    char* p = ws;
    u16* xwb     = (u16*)p;  p += (((size_t)(N + 64) * D * 2) + 255) & ~255ull;
    u16* hb      = (u16*)p;  p += (((size_t)(N + 64) * D * 2) + 255) & ~255ull;
    u16* Wp0     = (u16*)p;  p += ((size_t)128 * 128 * 2 + 255) & ~255ull;
    u16* Wp1     = (u16*)p;  p += ((size_t)128 * 128 * 2 + 255) & ~255ull;
    float* Wfp   = (float*)p; p += ((size_t)64 * 24 * 4 + 255) & ~255ull;
    u32* edgeBuf = (u32*)p;  p += (((size_t)nbuck * NB_EDGE * CAPSEG * 4) + 255) & ~255ull;  // 32 MB
    int* segCount = (int*)p; p += (((size_t)NB_EDGE * NBUCK_MAX * 4) + 255) & ~255ull;       // 1 MB
    int* col_idx = (int*)p;  p += (((size_t)nbuck * CAPB * 4) + 255) & ~255ull;              // 12.8 MB
    int2* rowse  = (int2*)p; p += (((size_t)N * 8) + 255) & ~255ull;
    float* out12 = (float*)p; p += (((size_t)N * 12 * 4) + 255) & ~255ull;                   // 4.8 MB
    int* goff    = (int*)p;

    // 1: single-pass placement + goff scan + Wf pack + W pack
    prep_place<<<NB_EDGE + 2 + 64, 512, 0, stream>>>(esrc, edst, E, nbuck, edgeBuf, segCount,
                                                     W0, W1, Wp0, Wp1, Wf, Wfp, gsz, G, goff);
    // 2: CSR finalize (binary-search compact) + layer-0 GEMM (fp32 A, fused cast)
    const int gemmGrid = (N + 63) / 64;
    finalize_gemm0<<<nbuck + gemmGrid, 256, 0, stream>>>(edgeBuf, segCount, rowse, col_idx, nbuck,
                                                         X, Wp0, xwb, N);
    // 3: fused layer-1 aggregate + layer-1 GEMM (writes xw2 into hb, incl. zero row N)
    agg_gemm1<<<N / 16 + 1, 256, 0, stream>>>(xwb, rowse, col_idx, b0, Wp1, hb, N);
    // 4: layer-2 aggregate fused with head -> out12
    agg_head<<<(N * 64 + 255) / 256, 256, 0, stream>>>(hb, rowse, col_idx, b1, Wfp, bfv, out12, N);
    // 5: per-graph mean
    graph_mean<<<G, 128, 0, stream>>>(out12, goff, out, G);
}